// Round 12
// baseline (273.299 us; speedup 1.0000x reference)
//
#include <hip/hip_runtime.h>

#define N_NODES   100000
#define N_EDGES   1600000
#define BSHIFT    9
#define NB        196        // ceil(100000 / 512)

typedef __attribute__((ext_vector_type(8))) short short8;
typedef __attribute__((ext_vector_type(4))) float f32x4;
typedef __attribute__((ext_vector_type(2))) float f32x2;

__device__ __forceinline__ unsigned short f2bf(float f) {
    unsigned u = __float_as_uint(f);
    u += 0x7FFF + ((u >> 16) & 1);          // round-to-nearest-even
    return (unsigned short)(u >> 16);
}

__device__ __forceinline__ int load_src(const int* e, int is64, int i) {
    return is64 ? e[2 * i] : e[i];
}
__device__ __forceinline__ int load_dst(const int* e, int is64, int i) {
    return is64 ? e[2 * (N_EDGES + i)] : e[N_EDGES + i];
}

// In-block edge-width self-detect: for int64 data all odd 32-bit words of the
// first 1024 entries are 0; for int32 they're random indices.
__device__ __forceinline__ int block_detect_is64(const int* e, int* s_nz) {
    if (threadIdx.x == 0) *s_nz = 0;
    __syncthreads();
    int v = 0;
    for (int i = threadIdx.x; i < 1024; i += 256) v |= e[2 * i + 1];
    if (v) atomicOr(s_nz, 1);
    __syncthreads();
    return (*s_nz == 0) ? 1 : 0;
}

// ---------------- phase A: bucket histogram + bf16/fp8 prep (one grid) ----------------
__global__ __launch_bounds__(256) void phaseA_kernel(
        const int* __restrict__ e, const float* __restrict__ x,
        const float* __restrict__ W1_l, const float* __restrict__ W1_r,
        const float* __restrict__ W2_l, const float* __restrict__ W2_r,
        int* __restrict__ bcnt, short* __restrict__ xb,
        unsigned int* __restrict__ xq,
        short* __restrict__ W1t, short* __restrict__ W2lt, short* __restrict__ W2rt) {
    const int blk = blockIdx.x;
    if (blk < 391) {
        __shared__ int s_nz;
        __shared__ int s_cnt[NB];
        for (int t = threadIdx.x; t < NB; t += 256) s_cnt[t] = 0;
        int is64 = block_detect_is64(e, &s_nz);   // includes the needed barrier
        __syncthreads();
        int i0 = blk * 4096;
        int n = min(4096, N_EDGES - i0);
        for (int t = 0; t < 16; t++) {
            int k = t * 256 + threadIdx.x;
            if (k < n) {
                int d = load_dst(e, is64, i0 + k);
                atomicAdd(&s_cnt[d >> BSHIFT], 1);
            }
        }
        __syncthreads();
        for (int t = threadIdx.x; t < NB; t += 256)
            if (s_cnt[t]) atomicAdd(&bcnt[t], s_cnt[t]);
    } else if (blk < 12891) {
        int t = (blk - 391) * 256 + threadIdx.x;
        int i = t * 4;
        float4 v = *(const float4*)&x[i];
        short4 o;
        o.x = (short)f2bf(v.x); o.y = (short)f2bf(v.y);
        o.z = (short)f2bf(v.z); o.w = (short)f2bf(v.w);
        *(short4*)&xb[i] = o;
        int w = __builtin_amdgcn_cvt_pk_fp8_f32(v.x, v.y, 0, false);
        w = __builtin_amdgcn_cvt_pk_fp8_f32(v.z, v.w, w, true);
        xq[t] = (unsigned int)w;
    } else {
        int i = (blk - 12891) * 256 + threadIdx.x;
        if (i < 32768) {
            int n = i >> 8, k = i & 255;
            float v = (k < 128) ? W1_l[k * 128 + n] : W1_r[(k - 128) * 128 + n];
            W1t[i] = (short)f2bf(v);
        } else if (i < 40960) {
            int j = i - 32768, n = j >> 7, k = j & 127;
            W2lt[j] = (short)f2bf(W2_l[k * 64 + n]);
        } else {
            int j = i - 40960, n = j >> 7, k = j & 127;
            W2rt[j] = (short)f2bf(W2_r[k * 64 + n]);
        }
    }
}

// ---------------- binscat: LDS bucket-sort + coalesced pair copy-out ----------------
__global__ __launch_bounds__(256) void binscat_kernel(
        const int* __restrict__ e, const int* __restrict__ bcnt,
        int* __restrict__ boff, int2* __restrict__ pairs) {
    __shared__ int2 s_pairs[4096];
    __shared__ int s_cnt[256], s_off[256], s_base[256], s_cur[256];
    __shared__ int s_nz;
    const int tid = threadIdx.x;
    s_cnt[tid] = 0;
    int is64 = block_detect_is64(e, &s_nz);
    __syncthreads();
    int i0 = blockIdx.x * 4096;
    int n = min(4096, N_EDGES - i0);
    int ls[16], ld[16];
    #pragma unroll
    for (int t = 0; t < 16; t++) {
        int k = t * 256 + tid;
        if (k < n) {
            ls[t] = load_src(e, is64, i0 + k);
            ld[t] = load_dst(e, is64, i0 + k);
            atomicAdd(&s_cnt[ld[t] >> BSHIFT], 1);
        }
    }
    __syncthreads();
    int lv = s_cnt[tid];
    s_off[tid] = lv;
    __syncthreads();
    for (int off = 1; off < 256; off <<= 1) {
        int t = (tid >= off) ? s_off[tid - off] : 0;
        __syncthreads();
        s_off[tid] += t;
        __syncthreads();
    }
    int excl = s_off[tid] - lv;
    int gv = (tid < NB) ? bcnt[tid] : 0;
    s_base[tid] = gv;
    __syncthreads();
    for (int off = 1; off < 256; off <<= 1) {
        int t = (tid >= off) ? s_base[tid - off] : 0;
        __syncthreads();
        s_base[tid] += t;
        __syncthreads();
    }
    int bst = s_base[tid] - gv;
    int gb = 0;
    if (tid < NB && lv > 0) gb = atomicAdd(&boff[tid], lv);
    s_off[tid] = excl;
    s_base[tid] = bst + gb;
    s_cur[tid] = excl;
    __syncthreads();
    #pragma unroll
    for (int t = 0; t < 16; t++) {
        int k = t * 256 + tid;
        if (k < n) {
            int pos = atomicAdd(&s_cur[ld[t] >> BSHIFT], 1);
            s_pairs[pos] = (int2){ls[t], ld[t]};
        }
    }
    __syncthreads();
    for (int j = tid; j < n; j += 256) {
        int2 pr = s_pairs[j];
        int b = pr.y >> BSHIFT;
        pairs[s_base[b] + (j - s_off[b])] = pr;
    }
}

// ---------------- fused CSR tail ----------------
__global__ __launch_bounds__(256) void fused_fill_kernel(
        const int* __restrict__ bcnt, const int2* __restrict__ pairs,
        int* __restrict__ deg_i, int* __restrict__ cursor,
        float* __restrict__ inv_deg, int* __restrict__ col) {
    __shared__ int ldeg[512];
    __shared__ int ssum[256];
    __shared__ int sp0;
    const int tid = threadIdx.x;
    const int b = blockIdx.x;
    const int nbase = b << BSHIFT;
    int gv = (tid < NB) ? bcnt[tid] : 0;
    ssum[tid] = gv;
    __syncthreads();
    for (int off = 1; off < 256; off <<= 1) {
        int t = (tid >= off) ? ssum[tid - off] : 0;
        __syncthreads();
        ssum[tid] += t;
        __syncthreads();
    }
    if (tid == b) sp0 = ssum[tid] - gv;
    ldeg[tid] = 0; ldeg[tid + 256] = 0;
    __syncthreads();
    const int p0 = sp0, cnt = bcnt[b];
    for (int j = tid; j < cnt; j += 256)
        atomicAdd(&ldeg[pairs[p0 + j].y - nbase], 1);
    __syncthreads();
    int d0 = ldeg[tid * 2], d1 = ldeg[tid * 2 + 1];
    int tsum = d0 + d1;
    ssum[tid] = tsum;
    __syncthreads();
    for (int off = 1; off < 256; off <<= 1) {
        int t = (tid >= off) ? ssum[tid - off] : 0;
        __syncthreads();
        ssum[tid] += t;
        __syncthreads();
    }
    int excl = ssum[tid] - tsum;
    int s0 = p0 + excl;
    int s1 = s0 + d0;
    ldeg[tid * 2] = s0;
    ldeg[tid * 2 + 1] = s1;
    int idx0 = nbase + tid * 2;
    if (idx0 < N_NODES) {
        deg_i[idx0] = d0;
        cursor[idx0] = s0;
        inv_deg[idx0] = 1.0f / fmaxf((float)d0, 1.0f);
    }
    if (idx0 + 1 < N_NODES) {
        deg_i[idx0 + 1] = d1;
        cursor[idx0 + 1] = s1;
        inv_deg[idx0 + 1] = 1.0f / fmaxf((float)d1, 1.0f);
    }
    __syncthreads();
    for (int j = tid; j < cnt; j += 256) {
        int2 pr = pairs[p0 + j];
        int pos = atomicAdd(&ldeg[pr.y - nbase], 1);
        col[pos] = pr.x;
    }
}

// ---------------- fp8 helpers ----------------
__device__ __forceinline__ void acc_fp8x8(float* acc, uint2 w) {
    f32x2 f;
    f = __builtin_amdgcn_cvt_pk_f32_fp8((int)w.x, false); acc[0] += f[0]; acc[1] += f[1];
    f = __builtin_amdgcn_cvt_pk_f32_fp8((int)w.x, true);  acc[2] += f[0]; acc[3] += f[1];
    f = __builtin_amdgcn_cvt_pk_f32_fp8((int)w.y, false); acc[4] += f[0]; acc[5] += f[1];
    f = __builtin_amdgcn_cvt_pk_f32_fp8((int)w.y, true);  acc[6] += f[0]; acc[7] += f[1];
}

// ---------------- fused layer 1: gather (fp8) + MFMA, no agg intermediate ----
// Block = 256 thr, iterates 16-row tiles. Per tile: block-wide gather of the
// 16 nodes into LDS (bf16, agg128's exact pattern), barrier, then each of the
// 4 waves MFMAs its 32-col quarter with B in 64 VGPRs. h = relu([agg|x]@W1+b1).
#define AGS 136   // LDS row stride in shorts: 272 B, 16B-aligned, conflict-free
__global__ __launch_bounds__(256, 3) void layer1_fused(
        const int* __restrict__ cursor, const int* __restrict__ deg_i,
        const int* __restrict__ col, const unsigned int* __restrict__ xq,
        const float* __restrict__ inv_deg, const short* __restrict__ xb,
        const short* __restrict__ W1t, const float* __restrict__ b1,
        short* __restrict__ h) {
    __shared__ short s_ag[16 * AGS];
    const int wave = threadIdx.x >> 6, lane = threadIdx.x & 63;
    const int m = lane & 15, q = lane >> 4;
    // persistent B quarter: cols wave*32 .. wave*32+32
    short8 breg[2][8];
    #pragma unroll
    for (int t = 0; t < 2; t++)
        #pragma unroll
        for (int c = 0; c < 8; c++)
            breg[t][c] = *(const short8*)(W1t + (size_t)(wave * 32 + t * 16 + m) * 256 + c * 32 + q * 8);
    float bias[2];
    #pragma unroll
    for (int t = 0; t < 2; t++) bias[t] = b1[wave * 32 + t * 16 + m];

    const int n16 = threadIdx.x >> 4;    // gather: node slot 0..15
    const int l16 = threadIdx.x & 15;    // gather: col slice

    for (int tile = blockIdx.x; tile < 6250; tile += gridDim.x) {
        // ---- gather phase (identical math to standalone agg128) ----
        {
            int node = tile * 16 + n16;
            int cnt = deg_i[node];
            int start = cursor[node];
            float acc[8] = {0.f};
            int k = 0;
            for (; k + 4 <= cnt; k += 4) {
                int s0 = col[start + k + 0];
                int s1 = col[start + k + 1];
                int s2 = col[start + k + 2];
                int s3 = col[start + k + 3];
                uint2 w0 = *(const uint2*)(xq + (size_t)s0 * 32 + l16 * 2);
                uint2 w1 = *(const uint2*)(xq + (size_t)s1 * 32 + l16 * 2);
                uint2 w2 = *(const uint2*)(xq + (size_t)s2 * 32 + l16 * 2);
                uint2 w3 = *(const uint2*)(xq + (size_t)s3 * 32 + l16 * 2);
                acc_fp8x8(acc, w0); acc_fp8x8(acc, w1);
                acc_fp8x8(acc, w2); acc_fp8x8(acc, w3);
            }
            for (; k < cnt; k++) {
                int s0 = col[start + k];
                uint2 w = *(const uint2*)(xq + (size_t)s0 * 32 + l16 * 2);
                acc_fp8x8(acc, w);
            }
            float sc = inv_deg[node];
            short8 o;
            #pragma unroll
            for (int j = 0; j < 8; j++) o[j] = (short)f2bf(acc[j] * sc);
            *(short8*)&s_ag[n16 * AGS + l16 * 8] = o;
        }
        __syncthreads();
        // ---- MFMA phase: this wave's 32-col quarter ----
        {
            const short* xrow = xb + (size_t)(tile * 16 + m) * 128;
            short8 a[8];
            #pragma unroll
            for (int c = 0; c < 4; c++) a[c] = *(const short8*)&s_ag[m * AGS + c * 32 + q * 8];
            #pragma unroll
            for (int c = 0; c < 4; c++) a[c + 4] = *(const short8*)(xrow + c * 32 + q * 8);
            f32x4 acc2[2];
            #pragma unroll
            for (int t = 0; t < 2; t++) acc2[t] = (f32x4){0.f, 0.f, 0.f, 0.f};
            #pragma unroll
            for (int c = 0; c < 8; c++)
                #pragma unroll
                for (int t = 0; t < 2; t++)
                    acc2[t] = __builtin_amdgcn_mfma_f32_16x16x32_bf16(a[c], breg[t][c], acc2[t], 0, 0, 0);
            #pragma unroll
            for (int t = 0; t < 2; t++) {
                int colc = wave * 32 + t * 16 + m;
                float bs = bias[t];
                #pragma unroll
                for (int r = 0; r < 4; r++) {
                    int rr = tile * 16 + q * 4 + r;
                    h[(size_t)rr * 128 + colc] = (short)f2bf(fmaxf(acc2[t][r] + bs, 0.f));
                }
            }
        }
        __syncthreads();   // s_ag reused next tile
    }
}

// layer-2: fp8 p rows (64 B), 8 lanes x 8 B per node; RMW on out.
__global__ __launch_bounds__(256) void agg64_kernel(
        const int* __restrict__ cursor, const int* __restrict__ deg_i,
        const int* __restrict__ col, const unsigned int* __restrict__ pq,
        const float* __restrict__ inv_deg, float* __restrict__ out) {
    int node = blockIdx.x * 32 + (threadIdx.x >> 3);
    int lane = threadIdx.x & 7;
    int cnt = deg_i[node];
    int start = cursor[node];
    float acc[8] = {0.f};
    int k = 0;
    for (; k + 4 <= cnt; k += 4) {
        int s0 = col[start + k + 0];
        int s1 = col[start + k + 1];
        int s2 = col[start + k + 2];
        int s3 = col[start + k + 3];
        uint2 w0 = *(const uint2*)(pq + (size_t)s0 * 16 + lane * 2);
        uint2 w1 = *(const uint2*)(pq + (size_t)s1 * 16 + lane * 2);
        uint2 w2 = *(const uint2*)(pq + (size_t)s2 * 16 + lane * 2);
        uint2 w3 = *(const uint2*)(pq + (size_t)s3 * 16 + lane * 2);
        acc_fp8x8(acc, w0); acc_fp8x8(acc, w1);
        acc_fp8x8(acc, w2); acc_fp8x8(acc, w3);
    }
    for (; k < cnt; k++) {
        int s0 = col[start + k];
        uint2 w = *(const uint2*)(pq + (size_t)s0 * 16 + lane * 2);
        acc_fp8x8(acc, w);
    }
    float sc = inv_deg[node];
    float* dst = out + (size_t)node * 64 + lane * 8;
    float4 o0 = *(float4*)dst;
    float4 o1 = *(float4*)(dst + 4);
    o0.x += acc[0] * sc; o0.y += acc[1] * sc; o0.z += acc[2] * sc; o0.w += acc[3] * sc;
    o1.x += acc[4] * sc; o1.y += acc[5] * sc; o1.z += acc[6] * sc; o1.w += acc[7] * sc;
    *(float4*)dst = o0;
    *(float4*)(dst + 4) = o1;
}

// Fused layer-2 projection: reads each h row once, emits p8 = fp8(h@W2_l)
// and out = h@W2_r + b2.
__global__ __launch_bounds__(256, 2) void proj2_mfma(
        const short* __restrict__ h, const short* __restrict__ W2lt,
        const short* __restrict__ W2rt, const float* __restrict__ b2,
        unsigned char* __restrict__ p8, float* __restrict__ out) {
    const int wave = threadIdx.x >> 6, lane = threadIdx.x & 63;
    const int m = lane & 15, q = lane >> 4;
    const int wid = blockIdx.x * 4 + wave;      // 0..2047
    short8 bl[4][4], br[4][4];
    #pragma unroll
    for (int t = 0; t < 4; t++)
        #pragma unroll
        for (int c = 0; c < 4; c++) {
            bl[t][c] = *(const short8*)(W2lt + (size_t)(t * 16 + m) * 128 + c * 32 + q * 8);
            br[t][c] = *(const short8*)(W2rt + (size_t)(t * 16 + m) * 128 + c * 32 + q * 8);
        }
    float bias[4];
    #pragma unroll
    for (int t = 0; t < 4; t++) bias[t] = b2[t * 16 + m];

    for (int tile = wid; tile < 6250; tile += 2048) {
        const short* hrow = h + (size_t)(tile * 16 + m) * 128;
        short8 a[4];
        #pragma unroll
        for (int c = 0; c < 4; c++) a[c] = *(const short8*)(hrow + c * 32 + q * 8);
        f32x4 accp[4], acco[4];
        #pragma unroll
        for (int t = 0; t < 4; t++) {
            accp[t] = (f32x4){0.f, 0.f, 0.f, 0.f};
            acco[t] = (f32x4){0.f, 0.f, 0.f, 0.f};
        }
        #pragma unroll
        for (int c = 0; c < 4; c++)
            #pragma unroll
            for (int t = 0; t < 4; t++) {
                accp[t] = __builtin_amdgcn_mfma_f32_16x16x32_bf16(a[c], bl[t][c], accp[t], 0, 0, 0);
                acco[t] = __builtin_amdgcn_mfma_f32_16x16x32_bf16(a[c], br[t][c], acco[t], 0, 0, 0);
            }
        #pragma unroll
        for (int t = 0; t < 4; t++) {
            int colc = t * 16 + m;
            #pragma unroll
            for (int r = 0; r < 4; r++) {
                int rr = tile * 16 + q * 4 + r;
                float pv = accp[t][r];
                int w = __builtin_amdgcn_cvt_pk_fp8_f32(pv, pv, 0, false);
                p8[(size_t)rr * 64 + colc] = (unsigned char)(w & 0xFF);
                out[(size_t)rr * 64 + colc] = acco[t][r] + bias[t];
            }
        }
    }
}

extern "C" void kernel_launch(void* const* d_in, const int* in_sizes, int n_in,
                              void* d_out, int out_size, void* d_ws, size_t ws_size,
                              hipStream_t stream) {
    const float* x    = (const float*)d_in[0];
    const int*   edge = (const int*)d_in[1];
    const float* W1_l = (const float*)d_in[2];
    const float* b1   = (const float*)d_in[3];
    const float* W1_r = (const float*)d_in[4];
    const float* W2_l = (const float*)d_in[5];
    const float* b2   = (const float*)d_in[6];
    const float* W2_r = (const float*)d_in[7];
    float* out = (float*)d_out;

    // ---- workspace layout (~85 MB) ----
    int* iw = (int*)d_ws;
    int* deg_i  = iw;                    // 100000
    int* cursor = iw + 100000;           // 100000 (row starts)
    int* col    = iw + 200000;           // 1600000
    int* bcnt   = iw + 1800000;          // 256
    int* boff   = iw + 1800256;          // 256 (zeroed with bcnt)
    float* inv_deg = (float*)iw + 1800832;   // 100096 -> 1900928
    int2*  pairs   = (int2*)(iw + 1900928); // 1.6M int2 (12.8 MB)
    short* xb   = (short*)(iw + 5100928);    // 12.8M bf16
    short* hb   = xb + 12800000;             // 12.8M bf16
    short* ag1  = hb + 12800000;             // 12.8M bf16 (p8 overlay region)
    short* W1t  = ag1 + 12800000;            // 32768
    short* W2lt = W1t + 32768;               // 8192
    short* W2rt = W2lt + 8192;               // 8192
    unsigned int* xq = (unsigned int*)hb;    // overlay: hb dead until layer1_fused writes it? NO --
    // xq must not alias hb (layer1_fused reads xq while writing hb). Use ag1 for xq:
    xq = (unsigned int*)ag1;                 // ag1 unused until p8; xq dead after layer1_fused
    unsigned char* p8 = (unsigned char*)ag1; // overlay: xq dead by proj2 time
    unsigned int*  pq = (unsigned int*)ag1;

    hipMemsetAsync(bcnt, 0, 512 * sizeof(int), stream);   // bcnt + boff

    // phase A: bucket histogram + bf16/fp8 prep, one grid
    phaseA_kernel<<<13083, 256, 0, stream>>>(edge, x, W1_l, W1_r, W2_l, W2_r,
                                             bcnt, xb, xq, W1t, W2lt, W2rt);
    // CSR build
    binscat_kernel<<<391, 256, 0, stream>>>(edge, bcnt, boff, pairs);
    fused_fill_kernel<<<NB, 256, 0, stream>>>(bcnt, pairs, deg_i, cursor, inv_deg, col);

    // layer 1 (fused gather + GEMM)
    layer1_fused<<<1024, 256, 0, stream>>>(cursor, deg_i, col, xq, inv_deg,
                                           xb, W1t, b1, hb);

    // layer 2
    proj2_mfma<<<512, 256, 0, stream>>>(hb, W2lt, W2rt, b2, p8, out);
    agg64_kernel<<<3125, 256, 0, stream>>>(cursor, deg_i, col, pq, inv_deg, out);
}

// Round 13
// 267.296 us; speedup vs baseline: 1.0225x; 1.0225x over previous
//
#include <hip/hip_runtime.h>

#define N_NODES   100000
#define N_EDGES   1600000
#define BSHIFT    9
#define NB        196        // ceil(100000 / 512)

typedef __attribute__((ext_vector_type(8))) short short8;
typedef __attribute__((ext_vector_type(4))) float f32x4;
typedef __attribute__((ext_vector_type(2))) float f32x2;

__device__ __forceinline__ unsigned short f2bf(float f) {
    unsigned u = __float_as_uint(f);
    u += 0x7FFF + ((u >> 16) & 1);          // round-to-nearest-even
    return (unsigned short)(u >> 16);
}

__device__ __forceinline__ int load_src(const int* e, int is64, int i) {
    return is64 ? e[2 * i] : e[i];
}
__device__ __forceinline__ int load_dst(const int* e, int is64, int i) {
    return is64 ? e[2 * (N_EDGES + i)] : e[N_EDGES + i];
}

// In-block edge-width self-detect: for int64 data all odd 32-bit words of the
// first 1024 entries are 0; for int32 they're random indices.
__device__ __forceinline__ int block_detect_is64(const int* e, int* s_nz) {
    if (threadIdx.x == 0) *s_nz = 0;
    __syncthreads();
    int v = 0;
    for (int i = threadIdx.x; i < 1024; i += 256) v |= e[2 * i + 1];
    if (v) atomicOr(s_nz, 1);
    __syncthreads();
    return (*s_nz == 0) ? 1 : 0;
}

// ---------------- phase A: bucket histogram + bf16/fp8 prep (one grid) ----------------
__global__ __launch_bounds__(256) void phaseA_kernel(
        const int* __restrict__ e, const float* __restrict__ x,
        const float* __restrict__ W1_l, const float* __restrict__ W1_r,
        const float* __restrict__ W2_l, const float* __restrict__ W2_r,
        int* __restrict__ bcnt, short* __restrict__ xb,
        unsigned int* __restrict__ xq,
        short* __restrict__ W1t, short* __restrict__ W2lt, short* __restrict__ W2rt) {
    const int blk = blockIdx.x;
    if (blk < 391) {
        __shared__ int s_nz;
        __shared__ int s_cnt[NB];
        for (int t = threadIdx.x; t < NB; t += 256) s_cnt[t] = 0;
        int is64 = block_detect_is64(e, &s_nz);   // includes the needed barrier
        __syncthreads();
        int i0 = blk * 4096;
        int n = min(4096, N_EDGES - i0);
        for (int t = 0; t < 16; t++) {
            int k = t * 256 + threadIdx.x;
            if (k < n) {
                int d = load_dst(e, is64, i0 + k);
                atomicAdd(&s_cnt[d >> BSHIFT], 1);
            }
        }
        __syncthreads();
        for (int t = threadIdx.x; t < NB; t += 256)
            if (s_cnt[t]) atomicAdd(&bcnt[t], s_cnt[t]);
    } else if (blk < 12891) {
        int t = (blk - 391) * 256 + threadIdx.x;
        int i = t * 4;
        float4 v = *(const float4*)&x[i];
        short4 o;
        o.x = (short)f2bf(v.x); o.y = (short)f2bf(v.y);
        o.z = (short)f2bf(v.z); o.w = (short)f2bf(v.w);
        *(short4*)&xb[i] = o;
        int w = __builtin_amdgcn_cvt_pk_fp8_f32(v.x, v.y, 0, false);
        w = __builtin_amdgcn_cvt_pk_fp8_f32(v.z, v.w, w, true);
        xq[t] = (unsigned int)w;
    } else {
        int i = (blk - 12891) * 256 + threadIdx.x;
        if (i < 32768) {
            int n = i >> 8, k = i & 255;
            float v = (k < 128) ? W1_l[k * 128 + n] : W1_r[(k - 128) * 128 + n];
            W1t[i] = (short)f2bf(v);
        } else if (i < 40960) {
            int j = i - 32768, n = j >> 7, k = j & 127;
            W2lt[j] = (short)f2bf(W2_l[k * 64 + n]);
        } else {
            int j = i - 40960, n = j >> 7, k = j & 127;
            W2rt[j] = (short)f2bf(W2_r[k * 64 + n]);
        }
    }
}

// ---------------- binscat: LDS bucket-sort + packed coalesced copy-out ------
// pairs entry: src (17 bits) | local-dst (9 bits) << 17.
__global__ __launch_bounds__(256) void binscat_kernel(
        const int* __restrict__ e, const int* __restrict__ bcnt,
        int* __restrict__ boff, int* __restrict__ pairs) {
    __shared__ int2 s_pairs[4096];
    __shared__ int s_cnt[256], s_off[256], s_base[256], s_cur[256];
    __shared__ int s_nz;
    const int tid = threadIdx.x;
    s_cnt[tid] = 0;
    int is64 = block_detect_is64(e, &s_nz);
    __syncthreads();
    int i0 = blockIdx.x * 4096;
    int n = min(4096, N_EDGES - i0);
    int ls[16], ld[16];
    #pragma unroll
    for (int t = 0; t < 16; t++) {
        int k = t * 256 + tid;
        if (k < n) {
            ls[t] = load_src(e, is64, i0 + k);
            ld[t] = load_dst(e, is64, i0 + k);
            atomicAdd(&s_cnt[ld[t] >> BSHIFT], 1);
        }
    }
    __syncthreads();
    int lv = s_cnt[tid];
    s_off[tid] = lv;
    __syncthreads();
    for (int off = 1; off < 256; off <<= 1) {
        int t = (tid >= off) ? s_off[tid - off] : 0;
        __syncthreads();
        s_off[tid] += t;
        __syncthreads();
    }
    int excl = s_off[tid] - lv;
    int gv = (tid < NB) ? bcnt[tid] : 0;
    s_base[tid] = gv;
    __syncthreads();
    for (int off = 1; off < 256; off <<= 1) {
        int t = (tid >= off) ? s_base[tid - off] : 0;
        __syncthreads();
        s_base[tid] += t;
        __syncthreads();
    }
    int bst = s_base[tid] - gv;
    int gb = 0;
    if (tid < NB && lv > 0) gb = atomicAdd(&boff[tid], lv);
    s_off[tid] = excl;
    s_base[tid] = bst + gb;
    s_cur[tid] = excl;
    __syncthreads();
    #pragma unroll
    for (int t = 0; t < 16; t++) {
        int k = t * 256 + tid;
        if (k < n) {
            int pos = atomicAdd(&s_cur[ld[t] >> BSHIFT], 1);
            s_pairs[pos] = (int2){ls[t], ld[t]};
        }
    }
    __syncthreads();
    for (int j = tid; j < n; j += 256) {
        int2 pr = s_pairs[j];
        int b = pr.y >> BSHIFT;
        pairs[s_base[b] + (j - s_off[b])] = pr.x | ((pr.y & 511) << 17);
    }
}

// ---------------- fused CSR tail (packed pairs) ----------------
__global__ __launch_bounds__(256) void fused_fill_kernel(
        const int* __restrict__ bcnt, const int* __restrict__ pairs,
        int* __restrict__ deg_i, int* __restrict__ cursor,
        float* __restrict__ inv_deg, int* __restrict__ col) {
    __shared__ int ldeg[512];
    __shared__ int ssum[256];
    __shared__ int sp0;
    const int tid = threadIdx.x;
    const int b = blockIdx.x;
    const int nbase = b << BSHIFT;
    int gv = (tid < NB) ? bcnt[tid] : 0;
    ssum[tid] = gv;
    __syncthreads();
    for (int off = 1; off < 256; off <<= 1) {
        int t = (tid >= off) ? ssum[tid - off] : 0;
        __syncthreads();
        ssum[tid] += t;
        __syncthreads();
    }
    if (tid == b) sp0 = ssum[tid] - gv;
    ldeg[tid] = 0; ldeg[tid + 256] = 0;
    __syncthreads();
    const int p0 = sp0, cnt = bcnt[b];
    for (int j = tid; j < cnt; j += 256)
        atomicAdd(&ldeg[pairs[p0 + j] >> 17], 1);
    __syncthreads();
    int d0 = ldeg[tid * 2], d1 = ldeg[tid * 2 + 1];
    int tsum = d0 + d1;
    ssum[tid] = tsum;
    __syncthreads();
    for (int off = 1; off < 256; off <<= 1) {
        int t = (tid >= off) ? ssum[tid - off] : 0;
        __syncthreads();
        ssum[tid] += t;
        __syncthreads();
    }
    int excl = ssum[tid] - tsum;
    int s0 = p0 + excl;
    int s1 = s0 + d0;
    ldeg[tid * 2] = s0;
    ldeg[tid * 2 + 1] = s1;
    int idx0 = nbase + tid * 2;
    if (idx0 < N_NODES) {
        deg_i[idx0] = d0;
        cursor[idx0] = s0;
        inv_deg[idx0] = 1.0f / fmaxf((float)d0, 1.0f);
    }
    if (idx0 + 1 < N_NODES) {
        deg_i[idx0 + 1] = d1;
        cursor[idx0 + 1] = s1;
        inv_deg[idx0 + 1] = 1.0f / fmaxf((float)d1, 1.0f);
    }
    __syncthreads();
    for (int j = tid; j < cnt; j += 256) {
        int pk = pairs[p0 + j];
        int pos = atomicAdd(&ldeg[pk >> 17], 1);
        col[pos] = pk & 0x1FFFF;
    }
}

// ---------------- fp8 helpers ----------------
__device__ __forceinline__ void acc_fp8x8(float* acc, uint2 w) {
    f32x2 f;
    f = __builtin_amdgcn_cvt_pk_f32_fp8((int)w.x, false); acc[0] += f[0]; acc[1] += f[1];
    f = __builtin_amdgcn_cvt_pk_f32_fp8((int)w.x, true);  acc[2] += f[0]; acc[3] += f[1];
    f = __builtin_amdgcn_cvt_pk_f32_fp8((int)w.y, false); acc[4] += f[0]; acc[5] += f[1];
    f = __builtin_amdgcn_cvt_pk_f32_fp8((int)w.y, true);  acc[6] += f[0]; acc[7] += f[1];
}

// layer-1: fp8 rows (128 B), 16 lanes x 8 B per node, 4-deep MLP unroll.
__global__ __launch_bounds__(256) void agg128_kernel(
        const int* __restrict__ cursor, const int* __restrict__ deg_i,
        const int* __restrict__ col, const unsigned int* __restrict__ xq,
        const float* __restrict__ inv_deg, short* __restrict__ agg) {
    int node = blockIdx.x * 16 + (threadIdx.x >> 4);
    int lane = threadIdx.x & 15;
    int cnt = deg_i[node];
    int start = cursor[node];
    float acc[8] = {0.f};
    int k = 0;
    for (; k + 4 <= cnt; k += 4) {
        int s0 = col[start + k + 0];
        int s1 = col[start + k + 1];
        int s2 = col[start + k + 2];
        int s3 = col[start + k + 3];
        uint2 w0 = *(const uint2*)(xq + (size_t)s0 * 32 + lane * 2);
        uint2 w1 = *(const uint2*)(xq + (size_t)s1 * 32 + lane * 2);
        uint2 w2 = *(const uint2*)(xq + (size_t)s2 * 32 + lane * 2);
        uint2 w3 = *(const uint2*)(xq + (size_t)s3 * 32 + lane * 2);
        acc_fp8x8(acc, w0); acc_fp8x8(acc, w1);
        acc_fp8x8(acc, w2); acc_fp8x8(acc, w3);
    }
    for (; k < cnt; k++) {
        int s0 = col[start + k];
        uint2 w = *(const uint2*)(xq + (size_t)s0 * 32 + lane * 2);
        acc_fp8x8(acc, w);
    }
    float sc = inv_deg[node];
    short8 o;
    #pragma unroll
    for (int j = 0; j < 8; j++) o[j] = (short)f2bf(acc[j] * sc);
    *(short8*)(agg + (size_t)node * 128 + lane * 8) = o;
}

// layer-2: fp8 p rows (64 B), 8 lanes x 8 B per node; RMW on out.
__global__ __launch_bounds__(256) void agg64_kernel(
        const int* __restrict__ cursor, const int* __restrict__ deg_i,
        const int* __restrict__ col, const unsigned int* __restrict__ pq,
        const float* __restrict__ inv_deg, float* __restrict__ out) {
    int node = blockIdx.x * 32 + (threadIdx.x >> 3);
    int lane = threadIdx.x & 7;
    int cnt = deg_i[node];
    int start = cursor[node];
    float acc[8] = {0.f};
    int k = 0;
    for (; k + 4 <= cnt; k += 4) {
        int s0 = col[start + k + 0];
        int s1 = col[start + k + 1];
        int s2 = col[start + k + 2];
        int s3 = col[start + k + 3];
        uint2 w0 = *(const uint2*)(pq + (size_t)s0 * 16 + lane * 2);
        uint2 w1 = *(const uint2*)(pq + (size_t)s1 * 16 + lane * 2);
        uint2 w2 = *(const uint2*)(pq + (size_t)s2 * 16 + lane * 2);
        uint2 w3 = *(const uint2*)(pq + (size_t)s3 * 16 + lane * 2);
        acc_fp8x8(acc, w0); acc_fp8x8(acc, w1);
        acc_fp8x8(acc, w2); acc_fp8x8(acc, w3);
    }
    for (; k < cnt; k++) {
        int s0 = col[start + k];
        uint2 w = *(const uint2*)(pq + (size_t)s0 * 16 + lane * 2);
        acc_fp8x8(acc, w);
    }
    float sc = inv_deg[node];
    float* dst = out + (size_t)node * 64 + lane * 8;
    float4 o0 = *(float4*)dst;
    float4 o1 = *(float4*)(dst + 4);
    o0.x += acc[0] * sc; o0.y += acc[1] * sc; o0.z += acc[2] * sc; o0.w += acc[3] * sc;
    o1.x += acc[4] * sc; o1.y += acc[5] * sc; o1.z += acc[6] * sc; o1.w += acc[7] * sc;
    *(float4*)dst = o0;
    *(float4*)(dst + 4) = o1;
}

// ---------------- persistent MFMA GEMMs (B cached in registers) ----------------
__global__ __launch_bounds__(256, 2) void gemm1_mfma(
        const short* __restrict__ agg1, const short* __restrict__ xb,
        const short* __restrict__ W1t, const float* __restrict__ b1,
        short* __restrict__ h) {
    const int wave = threadIdx.x >> 6, lane = threadIdx.x & 63;
    const int m = lane & 15, q = lane >> 4;
    const int wid = blockIdx.x * 4 + wave;      // 0..2047
    const int half = wid & 1;
    short8 breg[4][8];
    #pragma unroll
    for (int t = 0; t < 4; t++)
        #pragma unroll
        for (int c = 0; c < 8; c++)
            breg[t][c] = *(const short8*)(W1t + (size_t)(half * 64 + t * 16 + m) * 256 + c * 32 + q * 8);
    float bias[4];
    #pragma unroll
    for (int t = 0; t < 4; t++) bias[t] = b1[half * 64 + t * 16 + m];

    for (int tile = wid >> 1; tile < 6250; tile += 1024) {
        const short* arow = agg1 + (size_t)(tile * 16 + m) * 128;
        const short* xrow = xb + (size_t)(tile * 16 + m) * 128;
        short8 a[8];
        #pragma unroll
        for (int c = 0; c < 4; c++) a[c] = *(const short8*)(arow + c * 32 + q * 8);
        #pragma unroll
        for (int c = 0; c < 4; c++) a[c + 4] = *(const short8*)(xrow + c * 32 + q * 8);
        f32x4 acc[4];
        #pragma unroll
        for (int t = 0; t < 4; t++) acc[t] = (f32x4){0.f, 0.f, 0.f, 0.f};
        #pragma unroll
        for (int c = 0; c < 8; c++)
            #pragma unroll
            for (int t = 0; t < 4; t++)
                acc[t] = __builtin_amdgcn_mfma_f32_16x16x32_bf16(a[c], breg[t][c], acc[t], 0, 0, 0);
        #pragma unroll
        for (int t = 0; t < 4; t++) {
            int colc = half * 64 + t * 16 + m;
            #pragma unroll
            for (int r = 0; r < 4; r++) {
                int rr = tile * 16 + q * 4 + r;
                h[(size_t)rr * 128 + colc] = (short)f2bf(fmaxf(acc[t][r] + bias[t], 0.f));
            }
        }
    }
}

// Fused layer-2 projection: reads each h row once, emits p8 = fp8(h@W2_l)
// and out = h@W2_r + b2.
__global__ __launch_bounds__(256, 2) void proj2_mfma(
        const short* __restrict__ h, const short* __restrict__ W2lt,
        const short* __restrict__ W2rt, const float* __restrict__ b2,
        unsigned char* __restrict__ p8, float* __restrict__ out) {
    const int wave = threadIdx.x >> 6, lane = threadIdx.x & 63;
    const int m = lane & 15, q = lane >> 4;
    const int wid = blockIdx.x * 4 + wave;      // 0..2047
    short8 bl[4][4], br[4][4];
    #pragma unroll
    for (int t = 0; t < 4; t++)
        #pragma unroll
        for (int c = 0; c < 4; c++) {
            bl[t][c] = *(const short8*)(W2lt + (size_t)(t * 16 + m) * 128 + c * 32 + q * 8);
            br[t][c] = *(const short8*)(W2rt + (size_t)(t * 16 + m) * 128 + c * 32 + q * 8);
        }
    float bias[4];
    #pragma unroll
    for (int t = 0; t < 4; t++) bias[t] = b2[t * 16 + m];

    for (int tile = wid; tile < 6250; tile += 2048) {
        const short* hrow = h + (size_t)(tile * 16 + m) * 128;
        short8 a[4];
        #pragma unroll
        for (int c = 0; c < 4; c++) a[c] = *(const short8*)(hrow + c * 32 + q * 8);
        f32x4 accp[4], acco[4];
        #pragma unroll
        for (int t = 0; t < 4; t++) {
            accp[t] = (f32x4){0.f, 0.f, 0.f, 0.f};
            acco[t] = (f32x4){0.f, 0.f, 0.f, 0.f};
        }
        #pragma unroll
        for (int c = 0; c < 4; c++)
            #pragma unroll
            for (int t = 0; t < 4; t++) {
                accp[t] = __builtin_amdgcn_mfma_f32_16x16x32_bf16(a[c], bl[t][c], accp[t], 0, 0, 0);
                acco[t] = __builtin_amdgcn_mfma_f32_16x16x32_bf16(a[c], br[t][c], acco[t], 0, 0, 0);
            }
        #pragma unroll
        for (int t = 0; t < 4; t++) {
            int colc = t * 16 + m;
            #pragma unroll
            for (int r = 0; r < 4; r++) {
                int rr = tile * 16 + q * 4 + r;
                float pv = accp[t][r];
                int w = __builtin_amdgcn_cvt_pk_fp8_f32(pv, pv, 0, false);
                p8[(size_t)rr * 64 + colc] = (unsigned char)(w & 0xFF);
                out[(size_t)rr * 64 + colc] = acco[t][r] + bias[t];
            }
        }
    }
}

extern "C" void kernel_launch(void* const* d_in, const int* in_sizes, int n_in,
                              void* d_out, int out_size, void* d_ws, size_t ws_size,
                              hipStream_t stream) {
    const float* x    = (const float*)d_in[0];
    const int*   edge = (const int*)d_in[1];
    const float* W1_l = (const float*)d_in[2];
    const float* b1   = (const float*)d_in[3];
    const float* W1_r = (const float*)d_in[4];
    const float* W2_l = (const float*)d_in[5];
    const float* b2   = (const float*)d_in[6];
    const float* W2_r = (const float*)d_in[7];
    float* out = (float*)d_out;

    // ---- workspace layout (~78 MB) ----
    int* iw = (int*)d_ws;
    int* deg_i  = iw;                    // 100000
    int* cursor = iw + 100000;           // 100000 (row starts)
    int* col    = iw + 200000;           // 1600000
    int* bcnt   = iw + 1800000;          // 256
    int* boff   = iw + 1800256;          // 256 (zeroed with bcnt)
    float* inv_deg = (float*)iw + 1800832;   // 100096 -> 1900928
    int*   pairs   = iw + 1900928;           // 1.6M packed ints (6.4 MB)
    short* xb   = (short*)(iw + 3500928);    // 12.8M bf16
    short* hb   = xb + 12800000;             // 12.8M bf16
    short* ag1  = hb + 12800000;             // 12.8M bf16 (layer-1 agg)
    short* W1t  = ag1 + 12800000;            // 32768
    short* W2lt = W1t + 32768;               // 8192
    short* W2rt = W2lt + 8192;               // 8192
    unsigned int* xq = (unsigned int*)hb;    // overlay: hb dead until gemm1, xq dead after agg128
    unsigned char* p8 = (unsigned char*)ag1; // overlay: ag1 dead after gemm1
    unsigned int*  pq = (unsigned int*)ag1;

    hipMemsetAsync(bcnt, 0, 512 * sizeof(int), stream);   // bcnt + boff

    // phase A: bucket histogram + bf16/fp8 prep, one grid
    phaseA_kernel<<<13083, 256, 0, stream>>>(edge, x, W1_l, W1_r, W2_l, W2_r,
                                             bcnt, xb, xq, W1t, W2lt, W2rt);
    // CSR build
    binscat_kernel<<<391, 256, 0, stream>>>(edge, bcnt, boff, pairs);
    fused_fill_kernel<<<NB, 256, 0, stream>>>(bcnt, pairs, deg_i, cursor, inv_deg, col);

    // layer 1
    agg128_kernel<<<6250, 256, 0, stream>>>(cursor, deg_i, col, xq, inv_deg, ag1);
    gemm1_mfma<<<512, 256, 0, stream>>>(ag1, xb, W1t, b1, hb);

    // layer 2
    proj2_mfma<<<512, 256, 0, stream>>>(hb, W2lt, W2rt, b2, p8, out);
    agg64_kernel<<<3125, 256, 0, stream>>>(cursor, deg_i, col, pq, inv_deg, out);
}